// Round 2
// baseline (3978.060 us; speedup 1.0000x reference)
//
#include <hip/hip_runtime.h>

// EideticLinearLayer: out = X @ W^T + bias ; idx = searchsorted_left(quantiles[col], wx)
// X: [16384, 256] f32, W: [4096, 256] f32, bias: [4096], quantiles: [4096, 31]
// d_out: [16384*4096] out floats, then [16384*4096] index floats.

#define B_DIM 16384
#define K_DIM 256
#define N_DIM 4096
#define NQ 31

#define BM 128
#define BN 128
#define BK 16
#define SA 132   // padded LDS row stride in floats: 132*4=528B keeps 16B alignment, 2-way max bank aliasing

__global__ __launch_bounds__(256, 4)
void eidetic_fused(const float* __restrict__ X,
                   const float* __restrict__ W,
                   const float* __restrict__ bias,
                   const float* __restrict__ Q,
                   float* __restrict__ out,
                   float* __restrict__ idxo)
{
    // As+Bs staging; Qs aliases the same memory (only live after the K-loop).
    __shared__ __align__(16) char smem[2 * BK * SA * 4];   // 16896 B
    float (*As)[SA] = (float (*)[SA])smem;
    float (*Bs)[SA] = (float (*)[SA])(smem + BK * SA * 4);
    float* Qs = (float*)smem;                              // [NQ][128] transposed, 15872 B

    const int tid = threadIdx.x;
    const int tx = tid & 15;
    const int ty = tid >> 4;
    const int m0 = blockIdx.x * BM;
    const int n0 = blockIdx.y * BN;

    // staging map: 256 threads cover 64 rows x 16 cols as float4, x2 row halves
    const int lr = tid >> 2;          // 0..63
    const int lc = (tid & 3) << 2;    // 0,4,8,12

    float acc[8][8];
#pragma unroll
    for (int i = 0; i < 8; ++i)
#pragma unroll
        for (int j = 0; j < 8; ++j) acc[i][j] = 0.f;

    const float* Aptr = X + (size_t)(m0 + lr) * K_DIM + lc;
    const float* Bptr = W + (size_t)(n0 + lr) * K_DIM + lc;

    // prefetch tile 0
    float4 a0 = *(const float4*)(Aptr);
    float4 a1 = *(const float4*)(Aptr + (size_t)64 * K_DIM);
    float4 b0 = *(const float4*)(Bptr);
    float4 b1 = *(const float4*)(Bptr + (size_t)64 * K_DIM);

    for (int k0 = 0; k0 < K_DIM / BK; ++k0) {
        __syncthreads();   // previous compute phase done reading LDS
        As[lc + 0][lr] = a0.x;  As[lc + 1][lr] = a0.y;  As[lc + 2][lr] = a0.z;  As[lc + 3][lr] = a0.w;
        As[lc + 0][lr + 64] = a1.x;  As[lc + 1][lr + 64] = a1.y;  As[lc + 2][lr + 64] = a1.z;  As[lc + 3][lr + 64] = a1.w;
        Bs[lc + 0][lr] = b0.x;  Bs[lc + 1][lr] = b0.y;  Bs[lc + 2][lr] = b0.z;  Bs[lc + 3][lr] = b0.w;
        Bs[lc + 0][lr + 64] = b1.x;  Bs[lc + 1][lr + 64] = b1.y;  Bs[lc + 2][lr + 64] = b1.z;  Bs[lc + 3][lr + 64] = b1.w;
        __syncthreads();

        // prefetch next tile while computing this one ((k0+1)&15 wraps harmlessly on the last iter)
        const int kn = ((k0 + 1) & 15) * BK;
        a0 = *(const float4*)(Aptr + kn);
        a1 = *(const float4*)(Aptr + (size_t)64 * K_DIM + kn);
        b0 = *(const float4*)(Bptr + kn);
        b1 = *(const float4*)(Bptr + (size_t)64 * K_DIM + kn);

#pragma unroll
        for (int k = 0; k < BK; ++k) {
            float4 aA = *(const float4*)&As[k][ty * 8];
            float4 aB = *(const float4*)&As[k][ty * 8 + 4];
            float4 bA = *(const float4*)&Bs[k][tx * 4];        // cols tx*4 .. tx*4+3
            float4 bB = *(const float4*)&Bs[k][tx * 4 + 64];   // cols 64+tx*4 .. 64+tx*4+3
            float a[8] = {aA.x, aA.y, aA.z, aA.w, aB.x, aB.y, aB.z, aB.w};
            float b[8] = {bA.x, bA.y, bA.z, bA.w, bB.x, bB.y, bB.z, bB.w};
#pragma unroll
            for (int i = 0; i < 8; ++i)
#pragma unroll
                for (int j = 0; j < 8; ++j)
                    acc[i][j] = fmaf(a[i], b[j], acc[i][j]);
        }
    }

    // stage this block's quantiles TRANSPOSED into LDS: Qs[t*128 + col]
    __syncthreads();
    for (int idx = tid; idx < NQ * BN; idx += 256) {
        const int t = idx >> 7;          // 0..30
        const int col = idx & 127;
        Qs[idx] = Q[(size_t)(n0 + col) * NQ + t];
    }
    __syncthreads();

    float bias0[4], bias1[4];
    *(float4*)bias0 = *(const float4*)(bias + n0 + tx * 4);
    *(float4*)bias1 = *(const float4*)(bias + n0 + 64 + tx * 4);

    const float4* Qs4 = (const float4*)Qs;

    // two 4-row halves to cap register pressure
#pragma unroll
    for (int h = 0; h < 2; ++h) {
        unsigned int cnt[4][8];
#pragma unroll
        for (int i = 0; i < 4; ++i)
#pragma unroll
            for (int j = 0; j < 8; ++j) cnt[i][j] = 0u;

        // searchsorted side='left': index = count of bounds strictly < val
#pragma unroll 2
        for (int t = 0; t < NQ; ++t) {
            const float4 q0 = Qs4[t * 32 + tx];
            const float4 q1 = Qs4[t * 32 + 16 + tx];
#pragma unroll
            for (int i = 0; i < 4; ++i) {
                const int r = h * 4 + i;
                cnt[i][0] += (q0.x < acc[r][0]);
                cnt[i][1] += (q0.y < acc[r][1]);
                cnt[i][2] += (q0.z < acc[r][2]);
                cnt[i][3] += (q0.w < acc[r][3]);
                cnt[i][4] += (q1.x < acc[r][4]);
                cnt[i][5] += (q1.y < acc[r][5]);
                cnt[i][6] += (q1.z < acc[r][6]);
                cnt[i][7] += (q1.w < acc[r][7]);
            }
        }

#pragma unroll
        for (int i = 0; i < 4; ++i) {
            const int r = h * 4 + i;
            const size_t row = (size_t)(m0 + ty * 8 + r) * N_DIM + n0 + tx * 4;
            float4 o0, o1, c0, c1;
            o0.x = acc[r][0] + bias0[0];  o0.y = acc[r][1] + bias0[1];
            o0.z = acc[r][2] + bias0[2];  o0.w = acc[r][3] + bias0[3];
            o1.x = acc[r][4] + bias1[0];  o1.y = acc[r][5] + bias1[1];
            o1.z = acc[r][6] + bias1[2];  o1.w = acc[r][7] + bias1[3];
            c0.x = (float)cnt[i][0]; c0.y = (float)cnt[i][1]; c0.z = (float)cnt[i][2]; c0.w = (float)cnt[i][3];
            c1.x = (float)cnt[i][4]; c1.y = (float)cnt[i][5]; c1.z = (float)cnt[i][6]; c1.w = (float)cnt[i][7];
            *(float4*)(out + row)       = o0;
            *(float4*)(out + row + 64)  = o1;
            *(float4*)(idxo + row)      = c0;
            *(float4*)(idxo + row + 64) = c1;
        }
    }
}

extern "C" void kernel_launch(void* const* d_in, const int* in_sizes, int n_in,
                              void* d_out, int out_size, void* d_ws, size_t ws_size,
                              hipStream_t stream) {
    const float* x    = (const float*)d_in[0];
    const float* w    = (const float*)d_in[1];
    const float* bias = (const float*)d_in[2];
    const float* q    = (const float*)d_in[3];
    float* out  = (float*)d_out;
    float* idxo = out + (size_t)B_DIM * N_DIM;

    dim3 grid(B_DIM / BM, N_DIM / BN);
    hipLaunchKernelGGL(eidetic_fused, grid, dim3(256), 0, stream,
                       x, w, bias, q, out, idxo);
}